// Round 1
// baseline (361.064 us; speedup 1.0000x reference)
//
#include <hip/hip_runtime.h>
#include <math.h>

// Problem constants (from reference):
//   B = 16384 rows, N = 4096 cols, CELL_SIZES = linspace(2,100,10).astype(int32)
#define N_COLS 4096
#define WIN 200            // 2 * max cell size
#define CENTER 100

__global__ __launch_bounds__(256) void filter_kernel(
    const float* __restrict__ inp,   // [B, N]
    const float* __restrict__ ss,    // [N] search space (radians)
    const float* __restrict__ w,     // [1, 10]
    const float* __restrict__ bias,  // [1]
    float* __restrict__ out,         // [B, 1]
    int B)
{
    const int wave = threadIdx.x >> 6;
    const int lane = threadIdx.x & 63;
    const int row  = blockIdx.x * 4 + wave;
    if (row >= B) return;

    const float* __restrict__ x = inp + (size_t)row * N_COLS;

    // ---------------- Phase 1: top peak (strict local max, interior 1..N-2),
    // first-index tie-break to match jnp.argmax over where(mask, x, -inf).
    float bestv = -INFINITY;
    int   besti = 0;

    #pragma unroll 4
    for (int k = 0; k < 16; ++k) {
        const int p = k * 256 + lane * 4;           // 256 elems per wave-iteration
        const float4 v = *reinterpret_cast<const float4*>(x + p);
        int li = p - 1;          if (li < 0) li = 0;
        int ri = p + 4;          if (ri > N_COLS - 1) ri = N_COLS - 1;
        const float left  = x[li];    // L1 hit (neighbor lane's cache line)
        const float right = x[ri];

        // element p (needs p>=1 to be interior)
        if (p >= 1 && v.x > left && v.x > v.y) {
            if (v.x > bestv) { bestv = v.x; besti = p; }
        }
        if (v.y > v.x && v.y > v.z) {
            if (v.y > bestv) { bestv = v.y; besti = p + 1; }
        }
        if (v.z > v.y && v.z > v.w) {
            if (v.z > bestv) { bestv = v.z; besti = p + 2; }
        }
        // element p+3 (needs p+3 <= N-2 to be interior)
        if (p + 3 <= N_COLS - 2 && v.w > v.z && v.w > right) {
            if (v.w > bestv) { bestv = v.w; besti = p + 3; }
        }
    }

    // wave argmax with min-index tie-break (associative+commutative -> butterfly ok)
    #pragma unroll
    for (int off = 32; off >= 1; off >>= 1) {
        float ov = __shfl_xor(bestv, off, 64);
        int   oi = __shfl_xor(besti, off, 64);
        if (ov > bestv || (ov == bestv && oi < besti)) { bestv = ov; besti = oi; }
    }
    const int top1 = besti;   // all lanes agree; ==0 if no peak (matches argmax of all -inf)

    // ---------------- Phase 2: 200-wide circular window, 10 nested softmax features.
    // softmax is shift-invariant: use one global max M over the full window,
    // exp once, then each filter is two masked sum-reductions.
    float vv[4], sv[4];
    bool  valid[4];
    float lmax = -INFINITY;

    #pragma unroll
    for (int q = 0; q < 4; ++q) {
        const int j = lane + q * 64;
        valid[q] = (j < WIN);
        int pos = top1 - CENTER + j;               // in [-100, 4095+155] after clamp range
        if (pos < 0)        pos += N_COLS;
        if (pos >= N_COLS)  pos -= N_COLS;
        vv[q] = x[pos];
        sv[q] = ss[pos];
        if (valid[q] && vv[q] > lmax) lmax = vv[q];
    }
    #pragma unroll
    for (int off = 32; off >= 1; off >>= 1)
        lmax = fmaxf(lmax, __shfl_xor(lmax, off, 64));

    float e[4], t[4];
    #pragma unroll
    for (int q = 0; q < 4; ++q) {
        e[q] = valid[q] ? __expf(vv[q] - lmax) : 0.0f;
        t[q] = e[q] * sv[q];
    }

    const int cells[10] = {2, 12, 23, 34, 45, 56, 67, 78, 89, 100};
    float acc = 0.0f;
    #pragma unroll
    for (int f = 0; f < 10; ++f) {
        const int lo = CENTER - cells[f];
        const int hi = CENTER + cells[f];
        float s1 = 0.0f, s2 = 0.0f;
        #pragma unroll
        for (int q = 0; q < 4; ++q) {
            const int j = lane + q * 64;
            if (j >= lo && j < hi) { s1 += e[q]; s2 += t[q]; }
        }
        #pragma unroll
        for (int off = 32; off >= 1; off >>= 1) {
            s1 += __shfl_xor(s1, off, 64);
            s2 += __shfl_xor(s2, off, 64);
        }
        acc += (s2 / s1) * w[f];
    }

    if (lane == 0) {
        const float r = acc + bias[0];
        out[row] = r > 0.0f ? r : 0.0f;
    }
}

extern "C" void kernel_launch(void* const* d_in, const int* in_sizes, int n_in,
                              void* d_out, int out_size, void* d_ws, size_t ws_size,
                              hipStream_t stream) {
    const float* inp  = (const float*)d_in[0];   // [B, 4096]
    const float* ss   = (const float*)d_in[1];   // [4096]
    const float* w    = (const float*)d_in[2];   // [1, 10]
    const float* bias = (const float*)d_in[3];   // [1]
    float* out = (float*)d_out;                  // [B, 1]

    const int B = in_sizes[0] / N_COLS;
    const int blocks = (B + 3) / 4;              // 4 waves (rows) per 256-thread block
    filter_kernel<<<blocks, 256, 0, stream>>>(inp, ss, w, bias, out, B);
}